// Round 4
// baseline (159.586 us; speedup 1.0000x reference)
//
#include <hip/hip_runtime.h>
#include <hip/hip_cooperative_groups.h>

namespace cg = cooperative_groups;

#define EPS 1e-8f

constexpr int D = 384;
constexpr int P = 8;                          // parts per i-slab
constexpr int UNITS = D * P;                  // 3072 reduction units
constexpr int Q_PER_I = (D * D) / 4;          // 36864 float4 per i-slab
constexpr int Q_PER_UNIT = Q_PER_I / P;       // 4608 float4 per unit
constexpr int THREADS = 256;
constexpr int ITERS = Q_PER_UNIT / THREADS;   // 18
constexpr int J_PER_UNIT = (D / P);           // 48 j-rows per unit
constexpr int GRID = 1024;                    // 4 blocks/CU — under coop capacity
constexpr int UNITS_PER_BLOCK = UNITS / GRID; // 3 (exact)

__global__ __launch_bounds__(THREADS, 4) void fused_kernel(
    const float* __restrict__ x,
    const float* __restrict__ y,
    const float* __restrict__ z,
    const float* __restrict__ a,
    float* __restrict__ partials,
    float* __restrict__ out,
    int N) {
  cg::grid_group grid = cg::this_grid();

  const int b = blockIdx.x;
  const int tid = threadIdx.x;
  const int lane = tid & 63;
  const int w = tid >> 6;

  __shared__ float sm[THREADS / 64];
  __shared__ float ctx_s[D];

  const float4* z4 = reinterpret_cast<const float4*>(z);

  // ---- phase 1: three units per block ----
#pragma unroll
  for (int ui = 0; ui < UNITS_PER_BLOCK; ++ui) {
    const int unit = b + ui * GRID;
    const int i = unit >> 3;              // unit / 8
    const int part = unit & 7;            // unit % 8
    const float4* a4 = reinterpret_cast<const float4*>(a) +
                       (size_t)i * Q_PER_I + (size_t)part * Q_PER_UNIT;
    const int jbase = part * J_PER_UNIT;

    float acc = 0.0f;
#pragma unroll 6
    for (int it = 0; it < ITERS; ++it) {
      int q = it * THREADS + tid;         // [0, 4608)
      int jl = q / 96;                    // local j row (0..47)
      int k4 = q - jl * 96;               // float4 col within row (0..95)
      float4 av = a4[q];
      float4 zv = z4[k4];
      float yj = y[jbase + jl];
      acc += yj * (av.x * zv.x + av.y * zv.y + av.z * zv.z + av.w * zv.w);
    }
    for (int off = 32; off > 0; off >>= 1)
      acc += __shfl_down(acc, off);
    if (lane == 0) sm[w] = acc;
    __syncthreads();
    if (tid == 0) {
      float s = 0.0f;
#pragma unroll
      for (int k = 0; k < THREADS / 64; ++k) s += sm[k];
      partials[unit] = s;
    }
    __syncthreads();
  }

  grid.sync();

  // ---- phase 1.5: fold partials -> ctx in LDS (strided: D=384 > THREADS=256) ----
  for (int t = tid; t < D; t += THREADS) {
    float s = 0.0f;
#pragma unroll
    for (int p = 0; p < P; ++p) s += partials[t * P + p];
    ctx_s[t] = s;
  }
  __syncthreads();
  const float scale = 1.0f / (ctx_s[0] + EPS);
  const float4* c4 = reinterpret_cast<const float4*>(ctx_s);
  const float4 cv = c4[lane];
  float4 cv2 = make_float4(0.f, 0.f, 0.f, 0.f);
  if (lane < 32) cv2 = c4[64 + lane];

  // ---- phase 2: grid-stride rows, 1 row per wave ----
  const int wavesTotal = GRID * (THREADS / 64);
  for (int row = b * (THREADS / 64) + w; row < N; row += wavesTotal) {
    const float4* xr = reinterpret_cast<const float4*>(x) + (size_t)row * (D / 4);
    float4 xv = xr[lane];
    float s = xv.x * cv.x + xv.y * cv.y + xv.z * cv.z + xv.w * cv.w;
    if (lane < 32) {
      float4 xv2 = xr[64 + lane];
      s += xv2.x * cv2.x + xv2.y * cv2.y + xv2.z * cv2.z + xv2.w * cv2.w;
    }
    for (int off = 32; off > 0; off >>= 1)
      s += __shfl_down(s, off);
    if (lane == 0) out[row] = s * scale;
  }
}

extern "C" void kernel_launch(void* const* d_in, const int* in_sizes, int n_in,
                              void* d_out, int out_size, void* d_ws, size_t ws_size,
                              hipStream_t stream) {
  const float* x = (const float*)d_in[0];  // [N, 384]
  const float* y = (const float*)d_in[1];  // [384]
  const float* z = (const float*)d_in[2];  // [384]
  const float* a = (const float*)d_in[3];  // [384, 384, 384]
  float* out = (float*)d_out;              // [N]

  int N = in_sizes[0] / D;                 // 65536
  float* partials = (float*)d_ws;          // UNITS floats

  void* args[] = {(void*)&x, (void*)&y, (void*)&z, (void*)&a,
                  (void*)&partials, (void*)&out, (void*)&N};
  hipLaunchCooperativeKernel((void*)fused_kernel, dim3(GRID), dim3(THREADS),
                             args, 0, stream);
}

// Round 5
// 59.954 us; speedup vs baseline: 2.6618x; 2.6618x over previous
//
#include <hip/hip_runtime.h>

#define EPS 1e-8f

constexpr int D = 384;
constexpr int Q_PER_I = (D * D) / 4;        // 36864 float4 per i-slab
constexpr int P = 4;                        // partial blocks per i
constexpr int Q_PER_PART = Q_PER_I / P;     // 9216 float4 per block
constexpr int THREADS_A = 256;
constexpr int ITERS_A = Q_PER_PART / THREADS_A; // 36
constexpr int J_PER_PART = Q_PER_PART / (D / 4); // 96 j-rows per part

// Kernel A: partial reduction of context[i] = sum_{j,k} a[i,j,k]*y[j]*z[k]
// 1536 blocks (6/CU), each reads a contiguous 288 KB slab of a.
__global__ __launch_bounds__(THREADS_A) void ctx_partial_kernel(
    const float* __restrict__ a,
    const float* __restrict__ y,
    const float* __restrict__ z,
    float* __restrict__ partials) {
  const int b = blockIdx.x;
  const int i = b / P;
  const int part = b - i * P;
  const float4* a4 = reinterpret_cast<const float4*>(a) +
                     (size_t)i * Q_PER_I + (size_t)part * Q_PER_PART;
  const float4* z4 = reinterpret_cast<const float4*>(z);
  const int jbase = part * J_PER_PART;
  const int tid = threadIdx.x;

  float acc = 0.0f;
#pragma unroll 4
  for (int it = 0; it < ITERS_A; ++it) {
    int q = it * THREADS_A + tid;       // [0, 9216)
    int jl = q / 96;                    // local j row (0..95)
    int k4 = q - jl * 96;               // float4 col within row (0..95)
    float4 av = a4[q];
    float4 zv = z4[k4];
    float yj = y[jbase + jl];
    acc += yj * (av.x * zv.x + av.y * zv.y + av.z * zv.z + av.w * zv.w);
  }

  for (int off = 32; off > 0; off >>= 1)
    acc += __shfl_down(acc, off);

  __shared__ float sm[THREADS_A / 64];
  const int lane = tid & 63;
  const int w = tid >> 6;
  if (lane == 0) sm[w] = acc;
  __syncthreads();
  if (tid == 0) {
    float s = 0.0f;
#pragma unroll
    for (int k = 0; k < THREADS_A / 64; ++k) s += sm[k];
    partials[i * P + part] = s;
  }
}

// Kernel C': fold partials (P=4 -> one float4 per i) into ctx in LDS, then
// grid-stride matvec: 2048 blocks x 256 threads, 1 row per wave per iter.
__global__ __launch_bounds__(256) void score_kernel(
    const float* __restrict__ x,
    const float* __restrict__ partials,
    float* __restrict__ out,
    int N) {
  __shared__ float ctx_s[D];
  const int tid = threadIdx.x;

  // fold 1536 partials -> 384 context values (L2-resident reads)
  const float4* p4 = reinterpret_cast<const float4*>(partials);
  for (int t = tid; t < D; t += 256) {
    float4 v = p4[t];
    ctx_s[t] = v.x + v.y + v.z + v.w;
  }
  __syncthreads();

  const float scale = 1.0f / (ctx_s[0] + EPS);
  const int lane = tid & 63;
  const int w = tid >> 6;
  const float4* c4 = reinterpret_cast<const float4*>(ctx_s);
  const float4 cv = c4[lane];
  float4 cv2 = make_float4(0.f, 0.f, 0.f, 0.f);
  if (lane < 32) cv2 = c4[64 + lane];

  const int waveId = blockIdx.x * 4 + w;
  const int totalWaves = gridDim.x * 4;
  for (int row = waveId; row < N; row += totalWaves) {
    const float4* xr = reinterpret_cast<const float4*>(x) + (size_t)row * (D / 4);
    float4 xv = xr[lane];
    float s = xv.x * cv.x + xv.y * cv.y + xv.z * cv.z + xv.w * cv.w;
    if (lane < 32) {
      float4 xv2 = xr[64 + lane];
      s += xv2.x * cv2.x + xv2.y * cv2.y + xv2.z * cv2.z + xv2.w * cv2.w;
    }
    for (int off = 32; off > 0; off >>= 1)
      s += __shfl_down(s, off);
    if (lane == 0) out[row] = s * scale;
  }
}

extern "C" void kernel_launch(void* const* d_in, const int* in_sizes, int n_in,
                              void* d_out, int out_size, void* d_ws, size_t ws_size,
                              hipStream_t stream) {
  const float* x = (const float*)d_in[0];  // [N, 384]
  const float* y = (const float*)d_in[1];  // [384]
  const float* z = (const float*)d_in[2];  // [384]
  const float* a = (const float*)d_in[3];  // [384, 384, 384]
  float* out = (float*)d_out;              // [N]

  const int N = in_sizes[0] / D;           // 65536
  float* partials = (float*)d_ws;          // D*P floats

  ctx_partial_kernel<<<D * P, THREADS_A, 0, stream>>>(a, y, z, partials);
  score_kernel<<<2048, 256, 0, stream>>>(x, partials, out, N);
}